// Round 5
// baseline (296.350 us; speedup 1.0000x reference)
//
#include <hip/hip_runtime.h>

// Problem constants
#define NN 8192
#define EE 65536
#define K1 640   // layer1 GEMM depth: 512 (Z1) + 64 (sum_x) + 64 (x_self)
#define K2 480   // layer2 GEMM depth: 384 (Z2) + 48 (sum_h1) + 48 (h1_self)
#define ZS1 648  // LDS row stride for Zt1: mult of 4 (b128 align), 648%32=8 (bank spread)
#define ZS2 488  // LDS row stride for Zt2: 488%32=8

// ---------------------------------------------------------------------------
// Bilinear factorization (no per-edge weight matrices):
//   h1[n] = relu( [Z1[n] | sum_x[n] | x[n]] @ [nn1_w; nn1_b; root1] + bias1 )
//   where Z1[n,f,i] = sum_{e->n} ea[e][f] * x[src[e]][i].
//   Same for layer 2. GCN = CSR gather. W pre-transposed to [col][K] so the
//   per-block GEMM streams float4 from both LDS (Z row) and global (W row).
// ---------------------------------------------------------------------------

__global__ __launch_bounds__(256) void k_zero(int* __restrict__ p) {
    int i = blockIdx.x * 256 + threadIdx.x;
    ((int4*)p)[i] = make_int4(0, 0, 0, 0);  // grid covers exactly 8192 ints
}

__global__ __launch_bounds__(256) void k_count(const int* __restrict__ ei,
                                               int* __restrict__ cnt) {
    int e = blockIdx.x * 256 + threadIdx.x;
    if (e < EE) atomicAdd(&cnt[ei[EE + e]], 1);
}

// W transpose/pack: Wt1[o][k] (48 x 640), Wt2[o][k] (32 x 480).
__global__ __launch_bounds__(256) void k_wt(const float* __restrict__ nn1_w,
                                            const float* __restrict__ nn1_b,
                                            const float* __restrict__ root1,
                                            const float* __restrict__ nn2_w,
                                            const float* __restrict__ nn2_b,
                                            const float* __restrict__ root2,
                                            float* __restrict__ Wt1,
                                            float* __restrict__ Wt2) {
    int idx = blockIdx.x * 256 + threadIdx.x;
    if (idx < 48 * K1) {
        int o = idx / K1, k = idx - o * K1;
        float v;
        if (k < 512)      v = nn1_w[k * 48 + o];
        else if (k < 576) v = nn1_b[(k - 512) * 48 + o];
        else              v = root1[(k - 576) * 48 + o];
        Wt1[idx] = v;
    } else {
        int r = idx - 48 * K1;
        if (r < 32 * K2) {
            int o = r / K2, k = r - o * K2;
            float v;
            if (k < 384)      v = nn2_w[k * 32 + o];
            else if (k < 432) v = nn2_b[(k - 384) * 32 + o];
            else              v = root2[(k - 432) * 32 + o];
            Wt2[r] = v;
        }
    }
}

// Single block: exclusive scan cnt[8192] -> rowstart[8193] and cursor[8192].
__global__ __launch_bounds__(256) void k_scan(const int* __restrict__ cnt,
                                              int* __restrict__ rowstart,
                                              int* __restrict__ cursor) {
    __shared__ int part[256];
    const int t = threadIdx.x;
    const int base = t * 32;
    int local[32];
    int sum = 0;
#pragma unroll
    for (int k = 0; k < 32; k++) { local[k] = cnt[base + k]; sum += local[k]; }
    part[t] = sum;
    __syncthreads();
    if (t == 0) {
        int run = 0;
        for (int i = 0; i < 256; i++) { int c = part[i]; part[i] = run; run += c; }
    }
    __syncthreads();
    int run = part[t];
#pragma unroll
    for (int k = 0; k < 32; k++) {
        rowstart[base + k] = run;
        cursor[base + k] = run;
        run += local[k];
    }
    if (t == 255) rowstart[NN] = run;  // == EE
}

// dst-sorted edge arrays: ssrc (source node) and sea (edge features, coalesced).
__global__ __launch_bounds__(256) void k_scatter(const int* __restrict__ ei,
                                                 const float* __restrict__ ea,
                                                 int* __restrict__ cursor,
                                                 int* __restrict__ ssrc,
                                                 float* __restrict__ sea) {
    int e = blockIdx.x * 256 + threadIdx.x;
    if (e >= EE) return;
    int s = ei[e], d = ei[EE + e];
    int pos = atomicAdd(&cursor[d], 1);
    ssrc[pos] = s;
    const float4* a = (const float4*)(ea + (size_t)e * 8);
    float4* bp = (float4*)(sea + (size_t)pos * 8);
    bp[0] = a[0];
    bp[1] = a[1];
}

// ---------------------------------------------------------------------------
// k_L1: 16 nodes/block.
//  Phase A: each wave builds 4 nodes' Z rows with 4 interleaved edge chains
//           (wave-uniform node -> scalar ssrc/ea loads, vector x-row load).
//           Zt layout [node][K], stride ZS1: stores lane-contiguous.
//  Phase B: thread=(o,node): 3 cols, full K, float4-streamed. No reduction.
// ---------------------------------------------------------------------------
__global__ __launch_bounds__(256) void k_L1(const int* __restrict__ rowstart,
                                            const int* __restrict__ ssrc,
                                            const float* __restrict__ sea,
                                            const float* __restrict__ x,
                                            const float* __restrict__ Wt1,
                                            const float* __restrict__ bias1,
                                            float* __restrict__ h1) {
    __shared__ __align__(16) float Zt[16 * ZS1];  // 41.5 KB
    const int n0 = blockIdx.x * 16;
    {
        const int g = __builtin_amdgcn_readfirstlane(threadIdx.x >> 6);
        const int i = threadIdx.x & 63;
        float a[4][8];
        float as[4];
        int j0[4], j1[4];
#pragma unroll
        for (int m = 0; m < 4; m++) {
            int n = n0 + g * 4 + m;
            j0[m] = rowstart[n];
            j1[m] = rowstart[n + 1];
#pragma unroll
            for (int f = 0; f < 8; f++) a[m][f] = 0.f;
            as[m] = 0.f;
        }
        bool any = true;
        while (any) {
            any = false;
#pragma unroll
            for (int m = 0; m < 4; m++) {
                if (j0[m] < j1[m]) {
                    int s = ssrc[j0[m]];
                    float xv = x[(size_t)s * 64 + i];
                    const float4* q4 = (const float4*)(sea + (size_t)j0[m] * 8);
                    float4 e0 = q4[0], e1 = q4[1];
                    a[m][0] += e0.x * xv; a[m][1] += e0.y * xv;
                    a[m][2] += e0.z * xv; a[m][3] += e0.w * xv;
                    a[m][4] += e1.x * xv; a[m][5] += e1.y * xv;
                    a[m][6] += e1.z * xv; a[m][7] += e1.w * xv;
                    as[m] += xv;
                    j0[m]++;
                    any = true;
                }
            }
        }
#pragma unroll
        for (int m = 0; m < 4; m++) {
            const int nn = g * 4 + m;
            float* zr = Zt + nn * ZS1;
#pragma unroll
            for (int f = 0; f < 8; f++) zr[f * 64 + i] = a[m][f];
            zr[512 + i] = as[m];
            zr[576 + i] = x[(size_t)(n0 + nn) * 64 + i];
        }
    }
    __syncthreads();
    {
        const int o = threadIdx.x & 15;
        const int nn = threadIdx.x >> 4;
        const float* zr = Zt + nn * ZS1;
        const float* w0p = Wt1 + (size_t)o * K1;
        const float* w1p = w0p + 16 * K1;
        const float* w2p = w0p + 32 * K1;
        float c0 = 0.f, c1 = 0.f, c2 = 0.f;
#pragma unroll 2
        for (int k = 0; k < K1; k += 4) {
            float4 z = *(const float4*)&zr[k];
            float4 w0 = *(const float4*)&w0p[k];
            float4 w1 = *(const float4*)&w1p[k];
            float4 w2 = *(const float4*)&w2p[k];
            c0 += z.x * w0.x + z.y * w0.y + z.z * w0.z + z.w * w0.w;
            c1 += z.x * w1.x + z.y * w1.y + z.z * w1.z + z.w * w1.w;
            c2 += z.x * w2.x + z.y * w2.y + z.z * w2.z + z.w * w2.w;
        }
        const int n = n0 + nn;
        float v0 = c0 + bias1[o];
        float v1 = c1 + bias1[o + 16];
        float v2 = c2 + bias1[o + 32];
        h1[(size_t)n * 48 + o]      = v0 > 0.f ? v0 : 0.f;
        h1[(size_t)n * 48 + o + 16] = v1 > 0.f ? v1 : 0.f;
        h1[(size_t)n * 48 + o + 32] = v2 > 0.f ? v2 : 0.f;
    }
}

// ---------------------------------------------------------------------------
// k_L2: same pattern (K=480, 32 cols) + fused epilogue: h2 -> hmu/hls matvecs,
// dinv, out self-loop init. deg from rowstart (no cnt dependency).
// ---------------------------------------------------------------------------
__global__ __launch_bounds__(256) void k_L2(const int* __restrict__ rowstart,
                                            const int* __restrict__ ssrc,
                                            const float* __restrict__ sea,
                                            const float* __restrict__ h1,
                                            const float* __restrict__ Wt2,
                                            const float* __restrict__ bias2,
                                            const float* __restrict__ mu_w,
                                            const float* __restrict__ mu_b,
                                            const float* __restrict__ ls_w,
                                            const float* __restrict__ ls_b,
                                            float* __restrict__ hmu,
                                            float* __restrict__ hls,
                                            float* __restrict__ dinv,
                                            float* __restrict__ out) {
    __shared__ __align__(16) float Zt[16 * ZS2];  // 31.2 KB
    __shared__ float h2s[16 * 33];
    const int n0 = blockIdx.x * 16;
    {
        const int g = __builtin_amdgcn_readfirstlane(threadIdx.x >> 6);
        const int i = threadIdx.x & 63;
        float a[4][8];
        float as[4];
        int j0[4], j1[4];
#pragma unroll
        for (int m = 0; m < 4; m++) {
            int n = n0 + g * 4 + m;
            j0[m] = rowstart[n];
            j1[m] = rowstart[n + 1];
#pragma unroll
            for (int f = 0; f < 8; f++) a[m][f] = 0.f;
            as[m] = 0.f;
        }
        if (i < 48) {
            bool any = true;
            while (any) {
                any = false;
#pragma unroll
                for (int m = 0; m < 4; m++) {
                    if (j0[m] < j1[m]) {
                        int s = ssrc[j0[m]];
                        float hv = h1[(size_t)s * 48 + i];
                        const float4* q4 = (const float4*)(sea + (size_t)j0[m] * 8);
                        float4 e0 = q4[0], e1 = q4[1];
                        a[m][0] += e0.x * hv; a[m][1] += e0.y * hv;
                        a[m][2] += e0.z * hv; a[m][3] += e0.w * hv;
                        a[m][4] += e1.x * hv; a[m][5] += e1.y * hv;
                        a[m][6] += e1.z * hv; a[m][7] += e1.w * hv;
                        as[m] += hv;
                        j0[m]++;
                        any = true;
                    }
                }
            }
#pragma unroll
            for (int m = 0; m < 4; m++) {
                const int nn = g * 4 + m;
                float* zr = Zt + nn * ZS2;
#pragma unroll
                for (int f = 0; f < 8; f++) zr[f * 48 + i] = a[m][f];
                zr[384 + i] = as[m];
                zr[432 + i] = h1[(size_t)(n0 + nn) * 48 + i];
            }
        }
    }
    __syncthreads();
    {
        const int o = threadIdx.x & 15;
        const int nn = threadIdx.x >> 4;
        const float* zr = Zt + nn * ZS2;
        const float* w0p = Wt2 + (size_t)o * K2;
        const float* w1p = w0p + 16 * K2;
        float c0 = 0.f, c1 = 0.f;
#pragma unroll 2
        for (int k = 0; k < K2; k += 4) {
            float4 z = *(const float4*)&zr[k];
            float4 w0 = *(const float4*)&w0p[k];
            float4 w1 = *(const float4*)&w1p[k];
            c0 += z.x * w0.x + z.y * w0.y + z.z * w0.z + z.w * w0.w;
            c1 += z.x * w1.x + z.y * w1.y + z.z * w1.z + z.w * w1.w;
        }
        float v0 = c0 + bias2[o];
        float v1 = c1 + bias2[o + 16];
        h2s[nn * 33 + o]      = v0 > 0.f ? v0 : 0.f;
        h2s[nn * 33 + o + 16] = v1 > 0.f ? v1 : 0.f;
    }
    __syncthreads();
    {
        const int o = threadIdx.x & 15;
        const int nn = threadIdx.x >> 4;
        const int gn = n0 + nn;
        float am = 0.f, al = 0.f;
#pragma unroll
        for (int i = 0; i < 32; i++) {
            float hv = h2s[nn * 33 + i];
            am += hv * mu_w[i * 16 + o];
            al += hv * ls_w[i * 16 + o];
        }
        float d = (float)(rowstart[gn + 1] - rowstart[gn]) + 1.0f;
        float di = rsqrtf(d);
        if (o == 0) dinv[gn] = di;
        hmu[(size_t)gn * 16 + o] = am;
        hls[(size_t)gn * 16 + o] = al;
        out[(size_t)gn * 16 + o] = am / d + mu_b[o];
        out[(size_t)NN * 16 + (size_t)gn * 16 + o] = al / d + ls_b[o];
    }
}

// Final GCN neighbor sums: one wave per node, 4-way edge split, shfl reduce.
__global__ __launch_bounds__(256) void k_gcn(const int* __restrict__ rowstart,
                                             const int* __restrict__ ssrc,
                                             const float* __restrict__ hmu,
                                             const float* __restrict__ hls,
                                             const float* __restrict__ dinv,
                                             float* __restrict__ out) {
    const int wave = threadIdx.x >> 6;
    const int lane = threadIdx.x & 63;
    const int o = lane & 15, p = lane >> 4;
    const int d = blockIdx.x * 4 + wave;
    const int rs = rowstart[d], re = rowstart[d + 1];
    float am = 0.f, al = 0.f;
    for (int j = rs + p; j < re; j += 4) {
        int s = ssrc[j];
        float ds_ = dinv[s];
        am += hmu[(size_t)s * 16 + o] * ds_;
        al += hls[(size_t)s * 16 + o] * ds_;
    }
    am += __shfl_xor(am, 16); al += __shfl_xor(al, 16);
    am += __shfl_xor(am, 32); al += __shfl_xor(al, 32);
    if (p == 0) {
        float dd = dinv[d];
        out[(size_t)d * 16 + o] += am * dd;
        out[(size_t)NN * 16 + (size_t)d * 16 + o] += al * dd;
    }
}

extern "C" void kernel_launch(void* const* d_in, const int* in_sizes, int n_in,
                              void* d_out, int out_size, void* d_ws, size_t ws_size,
                              hipStream_t stream) {
    const float* x     = (const float*)d_in[0];
    const int*   ei    = (const int*)d_in[1];
    const float* ea    = (const float*)d_in[2];
    const float* nn1_w = (const float*)d_in[3];
    const float* nn1_b = (const float*)d_in[4];
    const float* root1 = (const float*)d_in[5];
    const float* bias1 = (const float*)d_in[6];
    const float* nn2_w = (const float*)d_in[7];
    const float* nn2_b = (const float*)d_in[8];
    const float* root2 = (const float*)d_in[9];
    const float* bias2 = (const float*)d_in[10];
    const float* mu_w  = (const float*)d_in[11];
    const float* mu_b  = (const float*)d_in[12];
    const float* ls_w  = (const float*)d_in[13];
    const float* ls_b  = (const float*)d_in[14];
    float* out = (float*)d_out;

    // Workspace layout: float4-consumed arrays first (16B alignment), ints last.
    float* W    = (float*)d_ws;
    float* Wt1  = W;                         // 48*640 = 30,720
    float* Wt2  = Wt1 + 48 * K1;             // 32*480 = 15,360
    float* sea  = Wt2 + 32 * K2;             // 524,288
    float* h1   = sea + 524288;              // 393,216
    float* hmu  = h1 + 393216;               // 131,072
    float* hls  = hmu + 131072;              // 131,072
    float* dinv = hls + 131072;              // 8,192
    int* cnt      = (int*)(dinv + 8192);     // 8,192
    int* rowstart = cnt + 8192;              // 8,193
    int* cursor   = rowstart + 8193;         // 8,192
    int* ssrc     = cursor + 8192;           // 65,536
    // total ~5.3 MB — everything L2-resident.

    k_zero<<<dim3(8), dim3(256), 0, stream>>>(cnt);
    k_count<<<dim3(EE / 256), dim3(256), 0, stream>>>(ei, cnt);
    k_wt<<<dim3((48 * K1 + 32 * K2 + 255) / 256), dim3(256), 0, stream>>>(
        nn1_w, nn1_b, root1, nn2_w, nn2_b, root2, Wt1, Wt2);
    k_scan<<<dim3(1), dim3(256), 0, stream>>>(cnt, rowstart, cursor);
    k_scatter<<<dim3(EE / 256), dim3(256), 0, stream>>>(ei, ea, cursor, ssrc, sea);
    k_L1<<<dim3(NN / 16), dim3(256), 0, stream>>>(rowstart, ssrc, sea, x,
                                                  Wt1, bias1, h1);
    k_L2<<<dim3(NN / 16), dim3(256), 0, stream>>>(rowstart, ssrc, sea, h1,
                                                  Wt2, bias2, mu_w, mu_b,
                                                  ls_w, ls_b, hmu, hls, dinv, out);
    k_gcn<<<dim3(NN / 4), dim3(256), 0, stream>>>(rowstart, ssrc,
                                                  hmu, hls, dinv, out);
}

// Round 6
// 176.243 us; speedup vs baseline: 1.6815x; 1.6815x over previous
//
#include <hip/hip_runtime.h>

// Problem constants
#define NN 8192
#define EE 65536
#define K1 640   // layer1 GEMM depth: 512 (Z1) + 64 (sum_x) + 64 (x_self)
#define K2 480   // layer2 GEMM depth: 384 (Z2) + 48 (sum_h1) + 48 (h1_self)
#define ZS1 648  // LDS row stride (floats): %32 = 8 -> nn-broadcast reads land on distinct banks
#define ZS2 488  // %32 = 8

// ---------------------------------------------------------------------------
// Bilinear factorization (no per-edge weight matrices):
//   h1[n] = relu( [Z1[n] | sum_x[n] | x[n]] @ [nn1_w; nn1_b; root1] + bias1 )
//   where Z1[n,f,i] = sum_{e->n} ea[e][f] * x[src[e]][i].
// Layer 2 identical with h1, K=480. GCN = CSR gather.
// Phase A: batch-8 prefetched edge gather (depth-2 dependence, 8-wide MLP).
// Phase B: W read in native [k][o] layout (coalesced 1-line loads), z via
//          LDS broadcast; K split 2-way + small LDS reduce.
// ---------------------------------------------------------------------------

__global__ __launch_bounds__(256) void k_zero(int* __restrict__ p) {
    int i = blockIdx.x * 256 + threadIdx.x;
    ((int4*)p)[i] = make_int4(0, 0, 0, 0);  // grid covers exactly 8192 ints
}

__global__ __launch_bounds__(256) void k_count(const int* __restrict__ ei,
                                               int* __restrict__ cnt) {
    int e = blockIdx.x * 256 + threadIdx.x;
    if (e < EE) atomicAdd(&cnt[ei[EE + e]], 1);
}

// Single block: exclusive scan cnt[8192] -> rowstart[8193] and cursor[8192].
__global__ __launch_bounds__(256) void k_scan(const int* __restrict__ cnt,
                                              int* __restrict__ rowstart,
                                              int* __restrict__ cursor) {
    __shared__ int part[256];
    const int t = threadIdx.x;
    const int base = t * 32;
    int local[32];
    int sum = 0;
#pragma unroll
    for (int k = 0; k < 32; k++) { local[k] = cnt[base + k]; sum += local[k]; }
    part[t] = sum;
    __syncthreads();
    if (t == 0) {
        int run = 0;
        for (int i = 0; i < 256; i++) { int c = part[i]; part[i] = run; run += c; }
    }
    __syncthreads();
    int run = part[t];
#pragma unroll
    for (int k = 0; k < 32; k++) {
        rowstart[base + k] = run;
        cursor[base + k] = run;
        run += local[k];
    }
    if (t == 255) rowstart[NN] = run;  // == EE
}

// dst-sorted edge arrays: ssrc (source node) and sea (edge features, coalesced).
__global__ __launch_bounds__(256) void k_scatter(const int* __restrict__ ei,
                                                 const float* __restrict__ ea,
                                                 int* __restrict__ cursor,
                                                 int* __restrict__ ssrc,
                                                 float* __restrict__ sea) {
    int e = blockIdx.x * 256 + threadIdx.x;
    if (e >= EE) return;
    int s = ei[e], d = ei[EE + e];
    int pos = atomicAdd(&cursor[d], 1);
    ssrc[pos] = s;
    const float4* a = (const float4*)(ea + (size_t)e * 8);
    float4* bp = (float4*)(sea + (size_t)pos * 8);
    bp[0] = a[0];
    bp[1] = a[1];
}

// ---------------------------------------------------------------------------
// k_L1: 8 nodes/block (grid 1024).
// ---------------------------------------------------------------------------
__global__ __launch_bounds__(256) void k_L1(const int* __restrict__ rowstart,
                                            const int* __restrict__ ssrc,
                                            const float* __restrict__ sea,
                                            const float* __restrict__ x,
                                            const float* __restrict__ nn1_w,
                                            const float* __restrict__ nn1_b,
                                            const float* __restrict__ root1,
                                            const float* __restrict__ bias1,
                                            float* __restrict__ h1) {
    __shared__ __align__(16) float Zt[8 * ZS1];   // 20.7 KB
    __shared__ float pacc[2][8][48];              // 3 KB
    const int n0 = blockIdx.x * 8;
    // ---- phase A: Z-build, 2 nodes per wave, batch-8 prefetch ----
    {
        const int wv = threadIdx.x >> 6;
        const int i = threadIdx.x & 63;
#pragma unroll
        for (int half = 0; half < 2; ++half) {
            const int nn = wv * 2 + half;
            const int n = n0 + nn;
            const int rs = rowstart[n], re = rowstart[n + 1];
            float a0 = 0, a1 = 0, a2 = 0, a3 = 0, a4 = 0, a5 = 0, a6 = 0, a7 = 0, as = 0;
            for (int base = rs; base < re; base += 8) {
                const int rem = re - base;
                int sj[8];
#pragma unroll
                for (int p = 0; p < 8; p++) {
                    int j = base + p;
                    sj[p] = ssrc[j < re ? j : re - 1];
                }
                float xv[8];
#pragma unroll
                for (int p = 0; p < 8; p++) xv[p] = x[(size_t)sj[p] * 64 + i];
#pragma unroll
                for (int p = 0; p < 8; p++) {
                    int j = base + p;
                    const float4* q4 = (const float4*)(sea + (size_t)(j < re ? j : re - 1) * 8);
                    float4 e0 = q4[0], e1 = q4[1];
                    float xx = (p < rem) ? xv[p] : 0.f;
                    a0 += e0.x * xx; a1 += e0.y * xx; a2 += e0.z * xx; a3 += e0.w * xx;
                    a4 += e1.x * xx; a5 += e1.y * xx; a6 += e1.z * xx; a7 += e1.w * xx;
                    as += xx;
                }
            }
            float* zr = Zt + nn * ZS1;
            zr[0 * 64 + i] = a0; zr[1 * 64 + i] = a1;
            zr[2 * 64 + i] = a2; zr[3 * 64 + i] = a3;
            zr[4 * 64 + i] = a4; zr[5 * 64 + i] = a5;
            zr[6 * 64 + i] = a6; zr[7 * 64 + i] = a7;
            zr[512 + i] = as;
            zr[576 + i] = x[(size_t)n * 64 + i];
        }
    }
    __syncthreads();
    // ---- phase B: [8 x 640] @ [640 x 48], W in native [k][o] layout ----
    {
        const int o  = threadIdx.x & 15;
        const int nn = (threadIdx.x >> 4) & 7;
        const int ks = threadIdx.x >> 7;  // 0/1
        const float* zr = Zt + nn * ZS1;
        const int k0 = ks * 320, k1 = k0 + 320;
        float c0 = 0.f, c1 = 0.f, c2 = 0.f;
        int ka1 = k1 < 512 ? k1 : 512;
#pragma unroll 4
        for (int k = k0; k < ka1; ++k) {
            float z = zr[k];
            const float* wp = nn1_w + k * 48 + o;
            c0 += z * wp[0]; c1 += z * wp[16]; c2 += z * wp[32];
        }
        int kb0 = k0 > 512 ? k0 : 512, kb1 = k1 < 576 ? k1 : 576;
#pragma unroll 4
        for (int k = kb0; k < kb1; ++k) {
            float z = zr[k];
            const float* wp = nn1_b + (k - 512) * 48 + o;
            c0 += z * wp[0]; c1 += z * wp[16]; c2 += z * wp[32];
        }
        int kc0 = k0 > 576 ? k0 : 576;
#pragma unroll 4
        for (int k = kc0; k < k1; ++k) {
            float z = zr[k];
            const float* wp = root1 + (k - 576) * 48 + o;
            c0 += z * wp[0]; c1 += z * wp[16]; c2 += z * wp[32];
        }
        pacc[ks][nn][o]      = c0;
        pacc[ks][nn][o + 16] = c1;
        pacc[ks][nn][o + 32] = c2;
    }
    __syncthreads();
    for (int r = threadIdx.x; r < 8 * 48; r += 256) {
        int nn = r / 48, o = r - nn * 48;
        float v = pacc[0][nn][o] + pacc[1][nn][o] + bias1[o];
        h1[(size_t)(n0 + nn) * 48 + o] = v > 0.f ? v : 0.f;
    }
}

// ---------------------------------------------------------------------------
// k_L2: 8 nodes/block (grid 1024), K=480, 32 cols + fused epilogue.
// ---------------------------------------------------------------------------
__global__ __launch_bounds__(256) void k_L2(const int* __restrict__ rowstart,
                                            const int* __restrict__ ssrc,
                                            const float* __restrict__ sea,
                                            const float* __restrict__ h1,
                                            const float* __restrict__ nn2_w,
                                            const float* __restrict__ nn2_b,
                                            const float* __restrict__ root2,
                                            const float* __restrict__ bias2,
                                            const float* __restrict__ mu_w,
                                            const float* __restrict__ mu_b,
                                            const float* __restrict__ ls_w,
                                            const float* __restrict__ ls_b,
                                            float* __restrict__ hmu,
                                            float* __restrict__ hls,
                                            float* __restrict__ dinv,
                                            float* __restrict__ out) {
    __shared__ __align__(16) float Zt[8 * ZS2];   // 15.6 KB
    __shared__ float pacc[2][8][33];
    __shared__ float h2s[8][33];
    const int n0 = blockIdx.x * 8;
    // ---- phase A ----
    {
        const int wv = threadIdx.x >> 6;
        const int i = threadIdx.x & 63;
#pragma unroll
        for (int half = 0; half < 2; ++half) {
            const int nn = wv * 2 + half;
            const int n = n0 + nn;
            if (i < 48) {
                const int rs = rowstart[n], re = rowstart[n + 1];
                float a0 = 0, a1 = 0, a2 = 0, a3 = 0, a4 = 0, a5 = 0, a6 = 0, a7 = 0, as = 0;
                for (int base = rs; base < re; base += 8) {
                    const int rem = re - base;
                    int sj[8];
#pragma unroll
                    for (int p = 0; p < 8; p++) {
                        int j = base + p;
                        sj[p] = ssrc[j < re ? j : re - 1];
                    }
                    float hv[8];
#pragma unroll
                    for (int p = 0; p < 8; p++) hv[p] = h1[(size_t)sj[p] * 48 + i];
#pragma unroll
                    for (int p = 0; p < 8; p++) {
                        int j = base + p;
                        const float4* q4 = (const float4*)(sea + (size_t)(j < re ? j : re - 1) * 8);
                        float4 e0 = q4[0], e1 = q4[1];
                        float xx = (p < rem) ? hv[p] : 0.f;
                        a0 += e0.x * xx; a1 += e0.y * xx; a2 += e0.z * xx; a3 += e0.w * xx;
                        a4 += e1.x * xx; a5 += e1.y * xx; a6 += e1.z * xx; a7 += e1.w * xx;
                        as += xx;
                    }
                }
                float* zr = Zt + nn * ZS2;
                zr[0 * 48 + i] = a0; zr[1 * 48 + i] = a1;
                zr[2 * 48 + i] = a2; zr[3 * 48 + i] = a3;
                zr[4 * 48 + i] = a4; zr[5 * 48 + i] = a5;
                zr[6 * 48 + i] = a6; zr[7 * 48 + i] = a7;
                zr[384 + i] = as;
                zr[432 + i] = h1[(size_t)n * 48 + i];
            }
        }
    }
    __syncthreads();
    // ---- phase B: [8 x 480] @ [480 x 32] ----
    {
        const int o  = threadIdx.x & 15;
        const int nn = (threadIdx.x >> 4) & 7;
        const int ks = threadIdx.x >> 7;
        const float* zr = Zt + nn * ZS2;
        const int k0 = ks * 240, k1 = k0 + 240;
        float c0 = 0.f, c1 = 0.f;
        int ka1 = k1 < 384 ? k1 : 384;
#pragma unroll 4
        for (int k = k0; k < ka1; ++k) {
            float z = zr[k];
            const float* wp = nn2_w + k * 32 + o;
            c0 += z * wp[0]; c1 += z * wp[16];
        }
        int kb0 = k0 > 384 ? k0 : 384, kb1 = k1 < 432 ? k1 : 432;
#pragma unroll 4
        for (int k = kb0; k < kb1; ++k) {
            float z = zr[k];
            const float* wp = nn2_b + (k - 384) * 32 + o;
            c0 += z * wp[0]; c1 += z * wp[16];
        }
        int kc0 = k0 > 432 ? k0 : 432;
#pragma unroll 4
        for (int k = kc0; k < k1; ++k) {
            float z = zr[k];
            const float* wp = root2 + (k - 432) * 32 + o;
            c0 += z * wp[0]; c1 += z * wp[16];
        }
        pacc[ks][nn][o]      = c0;
        pacc[ks][nn][o + 16] = c1;
    }
    __syncthreads();
    for (int r = threadIdx.x; r < 8 * 32; r += 256) {
        int nn = r >> 5, o = r & 31;
        float v = pacc[0][nn][o] + pacc[1][nn][o] + bias2[o];
        h2s[nn][o] = v > 0.f ? v : 0.f;
    }
    __syncthreads();
    if (threadIdx.x < 128) {
        const int o = threadIdx.x & 15;
        const int nn = threadIdx.x >> 4;
        const int gn = n0 + nn;
        float am = 0.f, al = 0.f;
#pragma unroll
        for (int i = 0; i < 32; i++) {
            float hv = h2s[nn][i];
            am += hv * mu_w[i * 16 + o];
            al += hv * ls_w[i * 16 + o];
        }
        float d = (float)(rowstart[gn + 1] - rowstart[gn]) + 1.0f;
        float di = rsqrtf(d);
        if (o == 0) dinv[gn] = di;
        hmu[(size_t)gn * 16 + o] = am;
        hls[(size_t)gn * 16 + o] = al;
        out[(size_t)gn * 16 + o] = am / d + mu_b[o];
        out[(size_t)NN * 16 + (size_t)gn * 16 + o] = al / d + ls_b[o];
    }
}

// Final GCN neighbor sums: one wave per node, 4-way edge split, shfl reduce.
__global__ __launch_bounds__(256) void k_gcn(const int* __restrict__ rowstart,
                                             const int* __restrict__ ssrc,
                                             const float* __restrict__ hmu,
                                             const float* __restrict__ hls,
                                             const float* __restrict__ dinv,
                                             float* __restrict__ out) {
    const int wave = threadIdx.x >> 6;
    const int lane = threadIdx.x & 63;
    const int o = lane & 15, p = lane >> 4;
    const int d = blockIdx.x * 4 + wave;
    const int rs = rowstart[d], re = rowstart[d + 1];
    float am = 0.f, al = 0.f;
    for (int j = rs + p; j < re; j += 4) {
        int s = ssrc[j];
        float ds_ = dinv[s];
        am += hmu[(size_t)s * 16 + o] * ds_;
        al += hls[(size_t)s * 16 + o] * ds_;
    }
    am += __shfl_xor(am, 16); al += __shfl_xor(al, 16);
    am += __shfl_xor(am, 32); al += __shfl_xor(al, 32);
    if (p == 0) {
        float dd = dinv[d];
        out[(size_t)d * 16 + o] += am * dd;
        out[(size_t)NN * 16 + (size_t)d * 16 + o] += al * dd;
    }
}

extern "C" void kernel_launch(void* const* d_in, const int* in_sizes, int n_in,
                              void* d_out, int out_size, void* d_ws, size_t ws_size,
                              hipStream_t stream) {
    const float* x     = (const float*)d_in[0];
    const int*   ei    = (const int*)d_in[1];
    const float* ea    = (const float*)d_in[2];
    const float* nn1_w = (const float*)d_in[3];
    const float* nn1_b = (const float*)d_in[4];
    const float* root1 = (const float*)d_in[5];
    const float* bias1 = (const float*)d_in[6];
    const float* nn2_w = (const float*)d_in[7];
    const float* nn2_b = (const float*)d_in[8];
    const float* root2 = (const float*)d_in[9];
    const float* bias2 = (const float*)d_in[10];
    const float* mu_w  = (const float*)d_in[11];
    const float* mu_b  = (const float*)d_in[12];
    const float* ls_w  = (const float*)d_in[13];
    const float* ls_b  = (const float*)d_in[14];
    float* out = (float*)d_out;

    // Workspace layout: float4-consumed arrays first (16B alignment), ints last.
    float* W    = (float*)d_ws;
    float* sea  = W;                         // 524,288
    float* h1   = sea + 524288;              // 393,216
    float* hmu  = h1 + 393216;               // 131,072
    float* hls  = hmu + 131072;              // 131,072
    float* dinv = hls + 131072;              // 8,192
    int* cnt      = (int*)(dinv + 8192);     // 8,192
    int* rowstart = cnt + 8192;              // 8,193
    int* cursor   = rowstart + 8193;         // 8,192
    int* ssrc     = cursor + 8192;           // 65,536
    // total ~5.1 MB — everything L2-resident.

    k_zero<<<dim3(8), dim3(256), 0, stream>>>(cnt);
    k_count<<<dim3(EE / 256), dim3(256), 0, stream>>>(ei, cnt);
    k_scan<<<dim3(1), dim3(256), 0, stream>>>(cnt, rowstart, cursor);
    k_scatter<<<dim3(EE / 256), dim3(256), 0, stream>>>(ei, ea, cursor, ssrc, sea);
    k_L1<<<dim3(NN / 8), dim3(256), 0, stream>>>(rowstart, ssrc, sea, x,
                                                 nn1_w, nn1_b, root1, bias1, h1);
    k_L2<<<dim3(NN / 8), dim3(256), 0, stream>>>(rowstart, ssrc, sea, h1,
                                                 nn2_w, nn2_b, root2, bias2,
                                                 mu_w, mu_b, ls_w, ls_b,
                                                 hmu, hls, dinv, out);
    k_gcn<<<dim3(NN / 4), dim3(256), 0, stream>>>(rowstart, ssrc,
                                                  hmu, hls, dinv, out);
}

// Round 7
// 154.650 us; speedup vs baseline: 1.9163x; 1.1396x over previous
//
#include <hip/hip_runtime.h>

// Problem constants
#define NN 8192
#define EE 65536
#define K1 640   // layer1 GEMM depth: 512 (Z1) + 64 (sum_x) + 64 (x_self)
#define K2 480   // layer2 GEMM depth: 384 (Z2) + 48 (sum_h1) + 48 (h1_self)
#define ZS1 652  // Zt row stride: mult of 4 (b128), 4*652%32=16 -> z b128 reads <=2-way
#define ZS2 492  // 4*492%32=16

// ---------------------------------------------------------------------------
// Bilinear factorization (no per-edge weight matrices):
//   h1[n] = relu( [Z1[n] | sum_x[n] | x[n]] @ [nn1_w; nn1_b; root1] + bias1 )
//   where Z1[n,f,i] = sum_{e->n} ea[e][f] * x[src[e]][i].
// Phase A: pair-interleaved batch-8 edge gather (16 loads in flight).
// Phase B: W staged to LDS in 12KB linear chunks; 4node x 3col register tile.
// ---------------------------------------------------------------------------

__global__ __launch_bounds__(256) void k_zero(int* __restrict__ p) {
    int i = blockIdx.x * 256 + threadIdx.x;
    ((int4*)p)[i] = make_int4(0, 0, 0, 0);  // grid covers exactly 8192 ints
}

__global__ __launch_bounds__(256) void k_count(const int* __restrict__ ei,
                                               int* __restrict__ cnt) {
    int e = blockIdx.x * 256 + threadIdx.x;
    if (e < EE) atomicAdd(&cnt[ei[EE + e]], 1);
}

// Single block: exclusive scan cnt[8192] -> rowstart[8193] and cursor[8192].
__global__ __launch_bounds__(256) void k_scan(const int* __restrict__ cnt,
                                              int* __restrict__ rowstart,
                                              int* __restrict__ cursor) {
    __shared__ int part[256];
    const int t = threadIdx.x;
    const int base = t * 32;
    int local[32];
    int sum = 0;
#pragma unroll
    for (int k = 0; k < 32; k++) { local[k] = cnt[base + k]; sum += local[k]; }
    part[t] = sum;
    __syncthreads();
    if (t == 0) {
        int run = 0;
        for (int i = 0; i < 256; i++) { int c = part[i]; part[i] = run; run += c; }
    }
    __syncthreads();
    int run = part[t];
#pragma unroll
    for (int k = 0; k < 32; k++) {
        rowstart[base + k] = run;
        cursor[base + k] = run;
        run += local[k];
    }
    if (t == 255) rowstart[NN] = run;  // == EE
}

// dst-sorted edge arrays: ssrc (source node) and sea (edge features, coalesced).
__global__ __launch_bounds__(256) void k_scatter(const int* __restrict__ ei,
                                                 const float* __restrict__ ea,
                                                 int* __restrict__ cursor,
                                                 int* __restrict__ ssrc,
                                                 float* __restrict__ sea) {
    int e = blockIdx.x * 256 + threadIdx.x;
    if (e >= EE) return;
    int s = ei[e], d = ei[EE + e];
    int pos = atomicAdd(&cursor[d], 1);
    ssrc[pos] = s;
    const float4* a = (const float4*)(ea + (size_t)e * 8);
    float4* bp = (float4*)(sea + (size_t)pos * 8);
    bp[0] = a[0];
    bp[1] = a[1];
}

// ---------------------------------------------------------------------------
// k_L1: 8 nodes/block (grid 1024).
// ---------------------------------------------------------------------------
__global__ __launch_bounds__(256) void k_L1(const int* __restrict__ rowstart,
                                            const int* __restrict__ ssrc,
                                            const float* __restrict__ sea,
                                            const float* __restrict__ x,
                                            const float* __restrict__ nn1_w,
                                            const float* __restrict__ nn1_b,
                                            const float* __restrict__ root1,
                                            const float* __restrict__ bias1,
                                            float* __restrict__ h1) {
    __shared__ __align__(16) float Zt[8 * ZS1];    // 20.9 KB
    __shared__ __align__(16) float Ws[64 * 48];    // 12.3 KB
    __shared__ float pacc[8][8][48];               // 12.3 KB
    const int n0 = blockIdx.x * 8;
    // ---- phase A: 1 node-pair per wave, batch-8 x 2 prefetch ----
    {
        const int wv = threadIdx.x >> 6;
        const int i = threadIdx.x & 63;
        const int nnA = wv * 2, nnB = nnA + 1;
        int jA = rowstart[n0 + nnA], eA = rowstart[n0 + nnA + 1];
        int jB = rowstart[n0 + nnB], eB = rowstart[n0 + nnB + 1];
        float aA[8] = {0, 0, 0, 0, 0, 0, 0, 0}, sA = 0.f;
        float aB[8] = {0, 0, 0, 0, 0, 0, 0, 0}, sB = 0.f;
        while (jA < eA || jB < eB) {
            int cjA[8], cjB[8];
#pragma unroll
            for (int p = 0; p < 8; p++) {
                int ja = jA + p; cjA[p] = (ja < eA) ? ja : 0;
                int jb = jB + p; cjB[p] = (jb < eB) ? jb : 0;
            }
            int sjA[8], sjB[8];
#pragma unroll
            for (int p = 0; p < 8; p++) { sjA[p] = ssrc[cjA[p]]; sjB[p] = ssrc[cjB[p]]; }
            float xvA[8], xvB[8];
#pragma unroll
            for (int p = 0; p < 8; p++) {
                xvA[p] = x[(size_t)sjA[p] * 64 + i];
                xvB[p] = x[(size_t)sjB[p] * 64 + i];
            }
#pragma unroll
            for (int p = 0; p < 8; p++) {
                {
                    const float4* q4 = (const float4*)(sea + (size_t)cjA[p] * 8);
                    float4 e0 = q4[0], e1 = q4[1];
                    float xx = (jA + p < eA) ? xvA[p] : 0.f;
                    aA[0] += e0.x * xx; aA[1] += e0.y * xx; aA[2] += e0.z * xx; aA[3] += e0.w * xx;
                    aA[4] += e1.x * xx; aA[5] += e1.y * xx; aA[6] += e1.z * xx; aA[7] += e1.w * xx;
                    sA += xx;
                }
                {
                    const float4* q4 = (const float4*)(sea + (size_t)cjB[p] * 8);
                    float4 e0 = q4[0], e1 = q4[1];
                    float xx = (jB + p < eB) ? xvB[p] : 0.f;
                    aB[0] += e0.x * xx; aB[1] += e0.y * xx; aB[2] += e0.z * xx; aB[3] += e0.w * xx;
                    aB[4] += e1.x * xx; aB[5] += e1.y * xx; aB[6] += e1.z * xx; aB[7] += e1.w * xx;
                    sB += xx;
                }
            }
            jA += 8; jB += 8;
        }
        float* zrA = Zt + nnA * ZS1;
        float* zrB = Zt + nnB * ZS1;
#pragma unroll
        for (int f = 0; f < 8; f++) { zrA[f * 64 + i] = aA[f]; zrB[f * 64 + i] = aB[f]; }
        zrA[512 + i] = sA; zrB[512 + i] = sB;
        zrA[576 + i] = x[(size_t)(n0 + nnA) * 64 + i];
        zrB[576 + i] = x[(size_t)(n0 + nnB) * 64 + i];
    }
    // ---- phase B: [8 x 640] @ [640 x 48], W staged per 64-row chunk ----
    const int o  = threadIdx.x & 15;
    const int q  = (threadIdx.x >> 4) & 1;
    const int ks = threadIdx.x >> 5;  // 0..7, wave-pair uniform-ish
    float acc[4][3];
#pragma unroll
    for (int m = 0; m < 4; m++)
#pragma unroll
        for (int cc = 0; cc < 3; cc++) acc[m][cc] = 0.f;
    for (int c = 0; c < 10; ++c) {
        __syncthreads();  // Zt ready (c=0) / prior chunk consumed (c>0)
        const float* src = (c < 8) ? nn1_w + c * 3072 : (c == 8 ? nn1_b : root1);
#pragma unroll
        for (int i2 = 0; i2 < 3; i2++) {
            int g = threadIdx.x + i2 * 256;
            *(float4*)&Ws[g * 4] = *(const float4*)&src[g * 4];
        }
        __syncthreads();
        const int kl0 = ks * 8;
        const int kg0 = c * 64 + kl0;
#pragma unroll
        for (int kk = 0; kk < 8; kk += 4) {
            const int kl = kl0 + kk, kg = kg0 + kk;
            float zc[4][4];
#pragma unroll
            for (int m = 0; m < 4; m++) {
                float4 z = *(const float4*)&Zt[(q * 4 + m) * ZS1 + kg];
                zc[m][0] = z.x; zc[m][1] = z.y; zc[m][2] = z.z; zc[m][3] = z.w;
            }
#pragma unroll
            for (int dk = 0; dk < 4; dk++) {
                float w0 = Ws[(kl + dk) * 48 + o];
                float w1 = Ws[(kl + dk) * 48 + o + 16];
                float w2 = Ws[(kl + dk) * 48 + o + 32];
#pragma unroll
                for (int m = 0; m < 4; m++) {
                    acc[m][0] += zc[m][dk] * w0;
                    acc[m][1] += zc[m][dk] * w1;
                    acc[m][2] += zc[m][dk] * w2;
                }
            }
        }
    }
#pragma unroll
    for (int m = 0; m < 4; m++) {
        pacc[ks][q * 4 + m][o]      = acc[m][0];
        pacc[ks][q * 4 + m][o + 16] = acc[m][1];
        pacc[ks][q * 4 + m][o + 32] = acc[m][2];
    }
    __syncthreads();
    for (int r = threadIdx.x; r < 8 * 48; r += 256) {
        int nn = r / 48, oc = r - nn * 48;
        float v = bias1[oc];
#pragma unroll
        for (int k = 0; k < 8; k++) v += pacc[k][nn][oc];
        h1[(size_t)(n0 + nn) * 48 + oc] = v > 0.f ? v : 0.f;
    }
}

// ---------------------------------------------------------------------------
// k_L2: 8 nodes/block (grid 1024), K=480 (5 chunks of 96x32) + fused epilogue.
// ---------------------------------------------------------------------------
__global__ __launch_bounds__(256) void k_L2(const int* __restrict__ rowstart,
                                            const int* __restrict__ ssrc,
                                            const float* __restrict__ sea,
                                            const float* __restrict__ h1,
                                            const float* __restrict__ nn2_w,
                                            const float* __restrict__ nn2_b,
                                            const float* __restrict__ root2,
                                            const float* __restrict__ bias2,
                                            const float* __restrict__ mu_w,
                                            const float* __restrict__ mu_b,
                                            const float* __restrict__ ls_w,
                                            const float* __restrict__ ls_b,
                                            float* __restrict__ hmu,
                                            float* __restrict__ hls,
                                            float* __restrict__ dinv,
                                            float* __restrict__ out) {
    __shared__ __align__(16) float Zt[8 * ZS2];    // 15.7 KB
    __shared__ __align__(16) float Ws[96 * 32];    // 12.3 KB
    __shared__ float pacc[8][8][32];               // 8.2 KB
    __shared__ float h2s[8][33];
    const int n0 = blockIdx.x * 8;
    // ---- phase A ----
    {
        const int wv = threadIdx.x >> 6;
        const int i = threadIdx.x & 63;
        if (i < 48) {
            const int nnA = wv * 2, nnB = nnA + 1;
            int jA = rowstart[n0 + nnA], eA = rowstart[n0 + nnA + 1];
            int jB = rowstart[n0 + nnB], eB = rowstart[n0 + nnB + 1];
            float aA[8] = {0, 0, 0, 0, 0, 0, 0, 0}, sA = 0.f;
            float aB[8] = {0, 0, 0, 0, 0, 0, 0, 0}, sB = 0.f;
            while (jA < eA || jB < eB) {
                int cjA[8], cjB[8];
#pragma unroll
                for (int p = 0; p < 8; p++) {
                    int ja = jA + p; cjA[p] = (ja < eA) ? ja : 0;
                    int jb = jB + p; cjB[p] = (jb < eB) ? jb : 0;
                }
                int sjA[8], sjB[8];
#pragma unroll
                for (int p = 0; p < 8; p++) { sjA[p] = ssrc[cjA[p]]; sjB[p] = ssrc[cjB[p]]; }
                float hvA[8], hvB[8];
#pragma unroll
                for (int p = 0; p < 8; p++) {
                    hvA[p] = h1[(size_t)sjA[p] * 48 + i];
                    hvB[p] = h1[(size_t)sjB[p] * 48 + i];
                }
#pragma unroll
                for (int p = 0; p < 8; p++) {
                    {
                        const float4* q4 = (const float4*)(sea + (size_t)cjA[p] * 8);
                        float4 e0 = q4[0], e1 = q4[1];
                        float xx = (jA + p < eA) ? hvA[p] : 0.f;
                        aA[0] += e0.x * xx; aA[1] += e0.y * xx; aA[2] += e0.z * xx; aA[3] += e0.w * xx;
                        aA[4] += e1.x * xx; aA[5] += e1.y * xx; aA[6] += e1.z * xx; aA[7] += e1.w * xx;
                        sA += xx;
                    }
                    {
                        const float4* q4 = (const float4*)(sea + (size_t)cjB[p] * 8);
                        float4 e0 = q4[0], e1 = q4[1];
                        float xx = (jB + p < eB) ? hvB[p] : 0.f;
                        aB[0] += e0.x * xx; aB[1] += e0.y * xx; aB[2] += e0.z * xx; aB[3] += e0.w * xx;
                        aB[4] += e1.x * xx; aB[5] += e1.y * xx; aB[6] += e1.z * xx; aB[7] += e1.w * xx;
                        sB += xx;
                    }
                }
                jA += 8; jB += 8;
            }
            float* zrA = Zt + nnA * ZS2;
            float* zrB = Zt + nnB * ZS2;
#pragma unroll
            for (int f = 0; f < 8; f++) { zrA[f * 48 + i] = aA[f]; zrB[f * 48 + i] = aB[f]; }
            zrA[384 + i] = sA; zrB[384 + i] = sB;
            zrA[432 + i] = h1[(size_t)(n0 + nnA) * 48 + i];
            zrB[432 + i] = h1[(size_t)(n0 + nnB) * 48 + i];
        }
    }
    // ---- phase B: [8 x 480] @ [480 x 32], W staged per 96-row chunk ----
    const int o  = threadIdx.x & 15;
    const int q  = (threadIdx.x >> 4) & 1;
    const int ks = threadIdx.x >> 5;  // 0..7
    float acc[4][2];
#pragma unroll
    for (int m = 0; m < 4; m++) { acc[m][0] = 0.f; acc[m][1] = 0.f; }
    for (int c = 0; c < 5; ++c) {
        __syncthreads();
#pragma unroll
        for (int i2 = 0; i2 < 3; i2++) {
            int g = threadIdx.x + i2 * 256;  // float4 index, 0..767
            const float* s4;
            if (c < 4)          s4 = nn2_w + c * 3072 + g * 4;
            else if (g < 384)   s4 = nn2_b + g * 4;
            else                s4 = root2 + (g - 384) * 4;
            *(float4*)&Ws[g * 4] = *(const float4*)s4;
        }
        __syncthreads();
        const int kl0 = ks * 12;
        const int kg0 = c * 96 + kl0;
#pragma unroll
        for (int kk = 0; kk < 12; kk += 4) {
            const int kl = kl0 + kk, kg = kg0 + kk;
            float zc[4][4];
#pragma unroll
            for (int m = 0; m < 4; m++) {
                float4 z = *(const float4*)&Zt[(q * 4 + m) * ZS2 + kg];
                zc[m][0] = z.x; zc[m][1] = z.y; zc[m][2] = z.z; zc[m][3] = z.w;
            }
#pragma unroll
            for (int dk = 0; dk < 4; dk++) {
                float w0 = Ws[(kl + dk) * 32 + o];
                float w1 = Ws[(kl + dk) * 32 + o + 16];
#pragma unroll
                for (int m = 0; m < 4; m++) {
                    acc[m][0] += zc[m][dk] * w0;
                    acc[m][1] += zc[m][dk] * w1;
                }
            }
        }
    }
#pragma unroll
    for (int m = 0; m < 4; m++) {
        pacc[ks][q * 4 + m][o]      = acc[m][0];
        pacc[ks][q * 4 + m][o + 16] = acc[m][1];
    }
    __syncthreads();
    {
        int nn = threadIdx.x >> 5, oc = threadIdx.x & 31;
        float v = bias2[oc];
#pragma unroll
        for (int k = 0; k < 8; k++) v += pacc[k][nn][oc];
        h2s[nn][oc] = v > 0.f ? v : 0.f;
    }
    __syncthreads();
    if (threadIdx.x < 128) {
        const int oc = threadIdx.x & 15;
        const int nn = threadIdx.x >> 4;
        const int gn = n0 + nn;
        float am = 0.f, al = 0.f;
#pragma unroll
        for (int i = 0; i < 32; i++) {
            float hv = h2s[nn][i];
            am += hv * mu_w[i * 16 + oc];
            al += hv * ls_w[i * 16 + oc];
        }
        float d = (float)(rowstart[gn + 1] - rowstart[gn]) + 1.0f;
        float di = rsqrtf(d);
        if (oc == 0) dinv[gn] = di;
        hmu[(size_t)gn * 16 + oc] = am;
        hls[(size_t)gn * 16 + oc] = al;
        out[(size_t)gn * 16 + oc] = am / d + mu_b[oc];
        out[(size_t)NN * 16 + (size_t)gn * 16 + oc] = al / d + ls_b[oc];
    }
}

// Final GCN neighbor sums: one wave per node, 4-way edge split, shfl reduce.
__global__ __launch_bounds__(256) void k_gcn(const int* __restrict__ rowstart,
                                             const int* __restrict__ ssrc,
                                             const float* __restrict__ hmu,
                                             const float* __restrict__ hls,
                                             const float* __restrict__ dinv,
                                             float* __restrict__ out) {
    const int wave = threadIdx.x >> 6;
    const int lane = threadIdx.x & 63;
    const int o = lane & 15, p = lane >> 4;
    const int d = blockIdx.x * 4 + wave;
    const int rs = rowstart[d], re = rowstart[d + 1];
    float am = 0.f, al = 0.f;
    for (int j = rs + p; j < re; j += 4) {
        int s = ssrc[j];
        float ds_ = dinv[s];
        am += hmu[(size_t)s * 16 + o] * ds_;
        al += hls[(size_t)s * 16 + o] * ds_;
    }
    am += __shfl_xor(am, 16); al += __shfl_xor(al, 16);
    am += __shfl_xor(am, 32); al += __shfl_xor(al, 32);
    if (p == 0) {
        float dd = dinv[d];
        out[(size_t)d * 16 + o] += am * dd;
        out[(size_t)NN * 16 + (size_t)d * 16 + o] += al * dd;
    }
}

extern "C" void kernel_launch(void* const* d_in, const int* in_sizes, int n_in,
                              void* d_out, int out_size, void* d_ws, size_t ws_size,
                              hipStream_t stream) {
    const float* x     = (const float*)d_in[0];
    const int*   ei    = (const int*)d_in[1];
    const float* ea    = (const float*)d_in[2];
    const float* nn1_w = (const float*)d_in[3];
    const float* nn1_b = (const float*)d_in[4];
    const float* root1 = (const float*)d_in[5];
    const float* bias1 = (const float*)d_in[6];
    const float* nn2_w = (const float*)d_in[7];
    const float* nn2_b = (const float*)d_in[8];
    const float* root2 = (const float*)d_in[9];
    const float* bias2 = (const float*)d_in[10];
    const float* mu_w  = (const float*)d_in[11];
    const float* mu_b  = (const float*)d_in[12];
    const float* ls_w  = (const float*)d_in[13];
    const float* ls_b  = (const float*)d_in[14];
    float* out = (float*)d_out;

    // Workspace layout: float4-consumed arrays first (16B alignment), ints last.
    float* W    = (float*)d_ws;
    float* sea  = W;                         // 524,288
    float* h1   = sea + 524288;              // 393,216
    float* hmu  = h1 + 393216;               // 131,072
    float* hls  = hmu + 131072;              // 131,072
    float* dinv = hls + 131072;              // 8,192
    int* cnt      = (int*)(dinv + 8192);     // 8,192
    int* rowstart = cnt + 8192;              // 8,193
    int* cursor   = rowstart + 8193;         // 8,192
    int* ssrc     = cursor + 8192;           // 65,536
    // total ~5.1 MB — everything L2-resident.

    k_zero<<<dim3(8), dim3(256), 0, stream>>>(cnt);
    k_count<<<dim3(EE / 256), dim3(256), 0, stream>>>(ei, cnt);
    k_scan<<<dim3(1), dim3(256), 0, stream>>>(cnt, rowstart, cursor);
    k_scatter<<<dim3(EE / 256), dim3(256), 0, stream>>>(ei, ea, cursor, ssrc, sea);
    k_L1<<<dim3(NN / 8), dim3(256), 0, stream>>>(rowstart, ssrc, sea, x,
                                                 nn1_w, nn1_b, root1, bias1, h1);
    k_L2<<<dim3(NN / 8), dim3(256), 0, stream>>>(rowstart, ssrc, sea, h1,
                                                 nn2_w, nn2_b, root2, bias2,
                                                 mu_w, mu_b, ls_w, ls_b,
                                                 hmu, hls, dinv, out);
    k_gcn<<<dim3(NN / 4), dim3(256), 0, stream>>>(rowstart, ssrc,
                                                  hmu, hls, dinv, out);
}